// Round 1
// baseline (122.882 us; speedup 1.0000x reference)
//
#include <hip/hip_runtime.h>

// ---------- constants (problem is fixed-shape) ----------
#define BB   16
#define PP   256
#define BP   4096        // B*P
#define DMODEL 1024
#define VV   1000
#define DLLM 4096
#define HH   16
#define DK   64
#define HDK  1024        // H*DK

using f32x4 = __attribute__((ext_vector_type(4))) float;
using s16x8 = __attribute__((ext_vector_type(8))) short;

__device__ __forceinline__ unsigned short f2bf(float f) {
    unsigned int u = __builtin_bit_cast(unsigned int, f);
    u = (u + 0x7FFFu + ((u >> 16) & 1u)) >> 16;   // RNE
    return (unsigned short)u;
}

// ---------- K1a: partial column sums of source/value (V x 4096 f32) ----------
__global__ void colsum_partial(const float* __restrict__ src0,
                               const float* __restrict__ src1,
                               float* __restrict__ part) {
    int col   = blockIdx.x * 256 + threadIdx.x;   // 0..4095
    int chunk = blockIdx.y;                        // 0..7 (125 rows each)
    int z     = blockIdx.z;                        // 0=source 1=value
    const float* src = z ? src1 : src0;
    int r0 = chunk * 125;
    float acc = 0.f;
    for (int r = 0; r < 125; ++r)
        acc += src[(size_t)(r0 + r) * DLLM + col];
    part[((z * 8 + chunk) * DLLM) + col] = acc;
}

// ---------- K1b: reduce partials -> sums[2][4096] ----------
__global__ void colsum_reduce(const float* __restrict__ part, float* __restrict__ sums) {
    int idx = blockIdx.x * 256 + threadIdx.x;      // 0..8191
    int z = idx >> 12, col = idx & 4095;
    float acc = 0.f;
    for (int c = 0; c < 8; ++c) acc += part[(size_t)(z * 8 + c) * DLLM + col];
    sums[idx] = acc;
}

// ---------- K2a: partial GEMV  part[z][chunk][c] = sum_r sums[z][r]*W[r][c] ----------
__global__ void gemv_partial(const float* __restrict__ Wk, const float* __restrict__ Wv,
                             const float* __restrict__ sums, float* __restrict__ part) {
    __shared__ float vec[128];
    int c     = blockIdx.x * 256 + threadIdx.x;    // 0..1023
    int chunk = blockIdx.y;                         // 0..31 (128 rows each)
    int z     = blockIdx.z;                         // 0=K 1=V
    const float* W = z ? Wv : Wk;
    const float* v = sums + z * DLLM;
    if (threadIdx.x < 128) vec[threadIdx.x] = v[chunk * 128 + threadIdx.x];
    __syncthreads();
    float acc = 0.f;
    int r0 = chunk * 128;
    for (int r = 0; r < 128; ++r)
        acc += vec[r] * W[(size_t)(r0 + r) * HDK + c];
    part[((z * 32 + chunk) * HDK) + c] = acc;
}

// ---------- K2b: reduce -> kvsum[0..1023]=Ksum, [1024..2047]=Vsum ----------
__global__ void gemv_reduce(const float* __restrict__ part,
                            const float* __restrict__ bk, const float* __restrict__ bv,
                            float* __restrict__ kvsum) {
    int idx = blockIdx.x * 256 + threadIdx.x;       // 0..2047
    int z = idx >> 10, c = idx & 1023;
    float acc = 0.f;
    for (int ch = 0; ch < 32; ++ch) acc += part[(size_t)(z * 32 + ch) * HDK + c];
    acc += (float)VV * (z ? bv[c] : bk[c]);
    kvsum[idx] = acc;
}

// ---------- K3a: cast f32 -> bf16 (vectorized, n4 = n/4) ----------
__global__ void cast_bf16(const float* __restrict__ src, unsigned short* __restrict__ dst, int n4) {
    int idx = blockIdx.x * 256 + threadIdx.x;
    if (idx >= n4) return;
    float4 v = reinterpret_cast<const float4*>(src)[idx];
    ushort4 o = make_ushort4(f2bf(v.x), f2bf(v.y), f2bf(v.z), f2bf(v.w));
    reinterpret_cast<ushort4*>(dst)[idx] = o;
}

// ---------- K3b: transpose + cast: src (R x C f32) -> dst (C x R bf16) ----------
__global__ void transpose_cast(const float* __restrict__ src, unsigned short* __restrict__ dst,
                               int R, int C) {
    __shared__ float tile[32][33];
    int tx = threadIdx.x, ty = threadIdx.y;         // 32 x 8
    int c0 = blockIdx.x * 32, r0 = blockIdx.y * 32;
#pragma unroll
    for (int j = 0; j < 4; ++j)
        tile[ty + j * 8][tx] = src[(size_t)(r0 + ty + j * 8) * C + c0 + tx];
    __syncthreads();
#pragma unroll
    for (int j = 0; j < 4; ++j)
        dst[(size_t)(c0 + ty + j * 8) * R + r0 + tx] = f2bf(tile[tx][ty + j * 8]);
}

// ---------- GEMM: C(f32 MxN) = A(bf16 MxK, row-major) * Bt(bf16 NxK, row-major) [+bias] ----------
#define BM 128
#define BN 128
#define BKT 64
#define LSTR 72   // 64 + 8 bf16 pad (16B) -> ~2-way LDS conflicts only

__global__ __launch_bounds__(256, 2)
void gemm_bf16(const unsigned short* __restrict__ A, const unsigned short* __restrict__ Bt,
               float* __restrict__ C, const float* __restrict__ bias,
               int M, int N, int K) {
    __shared__ unsigned short Asmem[BM * LSTR];
    __shared__ unsigned short Bsmem[BN * LSTR];
    const int t = threadIdx.x;
    const int wave = t >> 6, lane = t & 63;
    const int wr = wave >> 1, wc = wave & 1;        // 2x2 waves, each 64x64 out
    const int bm = blockIdx.y * BM;
    const int bn = blockIdx.x * BN;
    const int l15 = lane & 15;
    const int kgrp = lane >> 4;                     // 0..3

    f32x4 acc[4][4] = {};

    for (int k0 = 0; k0 < K; k0 += BKT) {
        // stage A,B tiles: 256 thr x 4 chunks x 16B each per matrix
#pragma unroll
        for (int i = 0; i < 4; ++i) {
            int cid = t + i * 256;                  // 0..1023
            int row = cid >> 3;
            int c16 = cid & 7;
            float4 va = *reinterpret_cast<const float4*>(A + (size_t)(bm + row) * K + k0 + c16 * 8);
            *reinterpret_cast<float4*>(&Asmem[row * LSTR + c16 * 8]) = va;
            float4 vb = *reinterpret_cast<const float4*>(Bt + (size_t)(bn + row) * K + k0 + c16 * 8);
            *reinterpret_cast<float4*>(&Bsmem[row * LSTR + c16 * 8]) = vb;
        }
        __syncthreads();
#pragma unroll
        for (int kk = 0; kk < 2; ++kk) {
            s16x8 af[4], bf[4];
#pragma unroll
            for (int m = 0; m < 4; ++m) {
                int row = wr * 64 + m * 16 + l15;
                af[m] = *reinterpret_cast<const s16x8*>(&Asmem[row * LSTR + kk * 32 + kgrp * 8]);
            }
#pragma unroll
            for (int n = 0; n < 4; ++n) {
                int col = wc * 64 + n * 16 + l15;
                bf[n] = *reinterpret_cast<const s16x8*>(&Bsmem[col * LSTR + kk * 32 + kgrp * 8]);
            }
#pragma unroll
            for (int m = 0; m < 4; ++m)
#pragma unroll
                for (int n = 0; n < 4; ++n)
                    acc[m][n] = __builtin_amdgcn_mfma_f32_16x16x32_bf16(af[m], bf[n], acc[m][n], 0, 0, 0);
        }
        __syncthreads();
    }

    // epilogue: C/D layout col = lane&15, row = (lane>>4)*4 + reg
#pragma unroll
    for (int m = 0; m < 4; ++m) {
        int grow = bm + wr * 64 + m * 16 + kgrp * 4;
#pragma unroll
        for (int n = 0; n < 4; ++n) {
            int gcol = bn + wc * 64 + n * 16 + l15;
            float bb = bias ? bias[gcol] : 0.f;
#pragma unroll
            for (int j = 0; j < 4; ++j)
                C[(size_t)(grow + j) * N + gcol] = acc[m][n][j] + bb;
        }
    }
}

// ---------- K5: per-(row,head) softmax over 64 dims; R = softmax(scale*(S+bq)*Ksum)*Vsum ----------
__global__ void softmax_kernel(const float* __restrict__ S, const float* __restrict__ bq,
                               const float* __restrict__ kvsum, unsigned short* __restrict__ R) {
    int t = threadIdx.x;
    int gw = blockIdx.x * 4 + (t >> 6);             // 0..65535  = row*16 + head
    int lane = t & 63;
    int i = gw >> 4, h = gw & 15;
    int c = h * DK + lane;
    float ks = kvsum[c];
    float vs = kvsum[HDK + c];
    float x = 0.125f * (S[(size_t)i * HDK + c] + bq[c]) * ks;
    float mx = x;
#pragma unroll
    for (int off = 32; off; off >>= 1) mx = fmaxf(mx, __shfl_xor(mx, off));
    float e = __expf(x - mx);
    float s = e;
#pragma unroll
    for (int off = 32; off; off >>= 1) s += __shfl_xor(s, off);
    float r = e / s * vs;
    R[(size_t)i * HDK + c] = f2bf(r);
}

// ---------- host launch ----------
extern "C" void kernel_launch(void* const* d_in, const int* in_sizes, int n_in,
                              void* d_out, int out_size, void* d_ws, size_t ws_size,
                              hipStream_t stream) {
    const float* target = (const float*)d_in[0];
    const float* source = (const float*)d_in[1];
    const float* value  = (const float*)d_in[2];
    const float* Wq = (const float*)d_in[3];
    const float* bq = (const float*)d_in[4];
    const float* Wk = (const float*)d_in[5];
    const float* bk = (const float*)d_in[6];
    const float* Wv = (const float*)d_in[7];
    const float* bv = (const float*)d_in[8];
    const float* Wo = (const float*)d_in[9];
    const float* bo = (const float*)d_in[10];
    float* out = (float*)d_out;

    char* ws = (char*)d_ws;
    float*          part1  = (float*)(ws);                    // 2*8*4096*4   = 256KB
    float*          sums   = (float*)(ws + 262144);           // 2*4096*4     = 32KB
    float*          part2  = (float*)(ws + 294912);           // 2*32*1024*4  = 256KB
    float*          kvsum  = (float*)(ws + 557056);           // 2*1024*4     = 8KB
    unsigned short* tgt_bf = (unsigned short*)(ws + 1048576);  // 4096*1024*2 = 8MB
    unsigned short* wq_t   = (unsigned short*)(ws + 9437184);  // 1024*1024*2 = 2MB
    unsigned short* wo_t   = (unsigned short*)(ws + 11534336); // 4096*1024*2 = 8MB
    float*          S      = (float*)(ws + 19922944);          // 4096*1024*4 = 16MB
    unsigned short* Rb     = (unsigned short*)(ws + 36700160); // 4096*1024*2 = 8MB

    // 1) column sums over V
    colsum_partial<<<dim3(16, 8, 2), 256, 0, stream>>>(source, value, part1);
    colsum_reduce<<<32, 256, 0, stream>>>(part1, sums);

    // 2) Ksum/Vsum GEMVs
    gemv_partial<<<dim3(4, 32, 2), 256, 0, stream>>>(Wk, Wv, sums, part2);
    gemv_reduce<<<8, 256, 0, stream>>>(part2, bk, bv, kvsum);

    // 3) casts / transposes to bf16
    cast_bf16<<<4096, 256, 0, stream>>>(target, tgt_bf, BP * DMODEL / 4);
    transpose_cast<<<dim3(HDK / 32, DMODEL / 32), dim3(32, 8), 0, stream>>>(Wq, wq_t, DMODEL, HDK);
    transpose_cast<<<dim3(DLLM / 32, HDK / 32), dim3(32, 8), 0, stream>>>(Wo, wo_t, HDK, DLLM);

    // 4) S = target @ Wq   (bias folded into softmax kernel)
    gemm_bf16<<<dim3(HDK / BN, BP / BM), 256, 0, stream>>>(tgt_bf, wq_t, S, nullptr, BP, HDK, DMODEL);

    // 5) softmax over head-dim, times Vsum -> R (bf16)
    softmax_kernel<<<BP * HH / 4, 256, 0, stream>>>(S, bq, kvsum, Rb);

    // 6) out = R @ Wo + bo
    gemm_bf16<<<dim3(DLLM / BN, BP / BM), 256, 0, stream>>>(Rb, wo_t, out, bo, BP, DLLM, HDK);
}

// Round 2
// 119.938 us; speedup vs baseline: 1.0245x; 1.0245x over previous
//
#include <hip/hip_runtime.h>

// ---------- constants (problem is fixed-shape) ----------
#define BB   16
#define PP   256
#define BP   4096        // B*P
#define DMODEL 1024
#define VV   1000
#define DLLM 4096
#define HH   16
#define DK   64
#define HDK  1024        // H*DK

using f32x4 = __attribute__((ext_vector_type(4))) float;
using s16x8 = __attribute__((ext_vector_type(8))) short;

__device__ __forceinline__ unsigned short f2bf(float f) {
    unsigned int u = __builtin_bit_cast(unsigned int, f);
    u = (u + 0x7FFFu + ((u >> 16) & 1u)) >> 16;   // RNE
    return (unsigned short)u;
}

// async global->LDS, 16B per lane. lds base must be wave-uniform; HW writes
// base + lane*16 (guide §5: m97 pattern).
__device__ __forceinline__ void gload_lds16(const unsigned short* g, unsigned short* lds) {
    __builtin_amdgcn_global_load_lds(
        (const __attribute__((address_space(1))) void*)g,
        (__attribute__((address_space(3))) void*)lds,
        16, 0, 0);
}

// ---------- K1a: partial column sums of source/value (V x 4096 f32) ----------
__global__ void colsum_partial(const float* __restrict__ src0,
                               const float* __restrict__ src1,
                               float* __restrict__ part) {
    int col   = blockIdx.x * 256 + threadIdx.x;   // 0..4095
    int chunk = blockIdx.y;                        // 0..7 (125 rows each)
    int z     = blockIdx.z;                        // 0=source 1=value
    const float* src = z ? src1 : src0;
    int r0 = chunk * 125;
    float acc = 0.f;
    for (int r = 0; r < 125; ++r)
        acc += src[(size_t)(r0 + r) * DLLM + col];
    part[((z * 8 + chunk) * DLLM) + col] = acc;
}

// ---------- K1b: reduce partials -> sums[2][4096] ----------
__global__ void colsum_reduce(const float* __restrict__ part, float* __restrict__ sums) {
    int idx = blockIdx.x * 256 + threadIdx.x;      // 0..8191
    int z = idx >> 12, col = idx & 4095;
    float acc = 0.f;
    for (int c = 0; c < 8; ++c) acc += part[(size_t)(z * 8 + c) * DLLM + col];
    sums[idx] = acc;
}

// ---------- K2a: partial GEMV  part[z][chunk][c] = sum_r sums[z][r]*W[r][c] ----------
__global__ void gemv_partial(const float* __restrict__ Wk, const float* __restrict__ Wv,
                             const float* __restrict__ sums, float* __restrict__ part) {
    __shared__ float vec[128];
    int c     = blockIdx.x * 256 + threadIdx.x;    // 0..1023
    int chunk = blockIdx.y;                         // 0..31 (128 rows each)
    int z     = blockIdx.z;                         // 0=K 1=V
    const float* W = z ? Wv : Wk;
    const float* v = sums + z * DLLM;
    if (threadIdx.x < 128) vec[threadIdx.x] = v[chunk * 128 + threadIdx.x];
    __syncthreads();
    float acc = 0.f;
    int r0 = chunk * 128;
    for (int r = 0; r < 128; ++r)
        acc += vec[r] * W[(size_t)(r0 + r) * HDK + c];
    part[((z * 32 + chunk) * HDK) + c] = acc;
}

// ---------- K2b: reduce -> kvsum[0..1023]=Ksum, [1024..2047]=Vsum ----------
__global__ void gemv_reduce(const float* __restrict__ part,
                            const float* __restrict__ bk, const float* __restrict__ bv,
                            float* __restrict__ kvsum) {
    int idx = blockIdx.x * 256 + threadIdx.x;       // 0..2047
    int z = idx >> 10, c = idx & 1023;
    float acc = 0.f;
    for (int ch = 0; ch < 32; ++ch) acc += part[(size_t)(z * 32 + ch) * HDK + c];
    acc += (float)VV * (z ? bv[c] : bk[c]);
    kvsum[idx] = acc;
}

// ---------- K3a: cast f32 -> bf16 (vectorized, n4 = n/4) ----------
__global__ void cast_bf16(const float* __restrict__ src, unsigned short* __restrict__ dst, int n4) {
    int idx = blockIdx.x * 256 + threadIdx.x;
    if (idx >= n4) return;
    float4 v = reinterpret_cast<const float4*>(src)[idx];
    ushort4 o = make_ushort4(f2bf(v.x), f2bf(v.y), f2bf(v.z), f2bf(v.w));
    reinterpret_cast<ushort4*>(dst)[idx] = o;
}

// ---------- K3b: transpose + cast: src (R x C f32) -> dst (C x R bf16) ----------
__global__ void transpose_cast(const float* __restrict__ src, unsigned short* __restrict__ dst,
                               int R, int C) {
    __shared__ float tile[32][33];
    int tx = threadIdx.x, ty = threadIdx.y;         // 32 x 8
    int c0 = blockIdx.x * 32, r0 = blockIdx.y * 32;
#pragma unroll
    for (int j = 0; j < 4; ++j)
        tile[ty + j * 8][tx] = src[(size_t)(r0 + ty + j * 8) * C + c0 + tx];
    __syncthreads();
#pragma unroll
    for (int j = 0; j < 4; ++j)
        dst[(size_t)(c0 + ty + j * 8) * R + r0 + tx] = f2bf(tile[tx][ty + j * 8]);
}

// ---------- GEMM (m97 structure): C = A(bf16 MxK) * Bt(bf16 NxK)^T ----------
// EPI=0: C(f32) = A*B^T + bias
// EPI=1: per-(row,head) softmax over the wave's 64-col head group, times Vsum,
//        write bf16 R. bias param = bq; kvsum[0:1024]=Ksum, [1024:2048]=Vsum.
#define BM 128
#define BN 128
#define BKT 64

template<int EPI>
__global__ __launch_bounds__(256, 2)
void gemm_k(const unsigned short* __restrict__ A, const unsigned short* __restrict__ Bt,
            float* __restrict__ C, const float* __restrict__ bias,
            const float* __restrict__ kvsum, unsigned short* __restrict__ R,
            int M, int N, int K) {
    __shared__ unsigned short Asmem[BM * BKT];   // 16 KB, linear (global_load_lds dest)
    __shared__ unsigned short Bsmem[BN * BKT];   // 16 KB
    const int t = threadIdx.x;
    const int wave = t >> 6, lane = t & 63;
    const int wr = wave >> 1, wc = wave & 1;        // 2x2 waves, 64x64 out each
    const int bm = blockIdx.y * BM;
    const int bn = blockIdx.x * BN;
    const int l15 = lane & 15;
    const int kgrp = lane >> 4;                     // 0..3

    // staging geometry: wave stages rows [wave*32, wave*32+32), 4 issues of
    // 8 rows; lane l covers row (l>>3), 8 bf16 at col (l&7)*8.
    const int srow = lane >> 3, scol = (lane & 7) * 8;
    const unsigned short* Ag = A + (size_t)(bm + wave * 32 + srow) * K + scol;
    const unsigned short* Bg = Bt + (size_t)(bn + wave * 32 + srow) * K + scol;

    f32x4 acc[4][4] = {};

    for (int ks = 0; ks < K / BKT; ++ks) {
#pragma unroll
        for (int i = 0; i < 4; ++i) {
            gload_lds16(Ag + (size_t)(i * 8) * K, &Asmem[(wave * 32 + i * 8) * BKT]);
            gload_lds16(Bg + (size_t)(i * 8) * K, &Bsmem[(wave * 32 + i * 8) * BKT]);
        }
        Ag += BKT; Bg += BKT;
        __syncthreads();   // compiler emits s_waitcnt vmcnt(0) before barrier
#pragma unroll
        for (int kk = 0; kk < 2; ++kk) {
            s16x8 af[4], bfr[4];
#pragma unroll
            for (int m = 0; m < 4; ++m)
                af[m] = *reinterpret_cast<const s16x8*>(
                    &Asmem[(wr * 64 + m * 16 + l15) * BKT + kk * 32 + kgrp * 8]);
#pragma unroll
            for (int n = 0; n < 4; ++n)
                bfr[n] = *reinterpret_cast<const s16x8*>(
                    &Bsmem[(wc * 64 + n * 16 + l15) * BKT + kk * 32 + kgrp * 8]);
#pragma unroll
            for (int m = 0; m < 4; ++m)
#pragma unroll
                for (int n = 0; n < 4; ++n)
                    acc[m][n] = __builtin_amdgcn_mfma_f32_16x16x32_bf16(af[m], bfr[n], acc[m][n], 0, 0, 0);
        }
        __syncthreads();
    }

    // C/D layout: col = lane&15, row = (lane>>4)*4 + reg j  (guide §3, m89/m91)
    if (EPI == 0) {
#pragma unroll
        for (int m = 0; m < 4; ++m) {
            int grow = bm + wr * 64 + m * 16 + kgrp * 4;
#pragma unroll
            for (int n = 0; n < 4; ++n) {
                int gcol = bn + wc * 64 + n * 16 + l15;
                float bb = bias[gcol];
#pragma unroll
                for (int j = 0; j < 4; ++j)
                    C[(size_t)(grow + j) * N + gcol] = acc[m][n][j] + bb;
            }
        }
    } else {
        // wave's 64-col span = exactly one head (bn, wc*64 both 64-aligned).
        // softmax over the head = reduce over n (4 regs) + 16-lane group shfl.
        float bqv[4], ksv[4], vsv[4];
#pragma unroll
        for (int n = 0; n < 4; ++n) {
            int col = bn + wc * 64 + n * 16 + l15;
            bqv[n] = bias[col];
            ksv[n] = kvsum[col];
            vsv[n] = kvsum[HDK + col];
        }
#pragma unroll
        for (int m = 0; m < 4; ++m) {
            int grow = bm + wr * 64 + m * 16 + kgrp * 4;
#pragma unroll
            for (int j = 0; j < 4; ++j) {
                float x[4];
#pragma unroll
                for (int n = 0; n < 4; ++n)
                    x[n] = 0.125f * (acc[m][n][j] + bqv[n]) * ksv[n];
                float mx = fmaxf(fmaxf(x[0], x[1]), fmaxf(x[2], x[3]));
#pragma unroll
                for (int off = 8; off; off >>= 1) mx = fmaxf(mx, __shfl_xor(mx, off));
                float e[4], s = 0.f;
#pragma unroll
                for (int n = 0; n < 4; ++n) { e[n] = __expf(x[n] - mx); s += e[n]; }
#pragma unroll
                for (int off = 8; off; off >>= 1) s += __shfl_xor(s, off);
                float inv = 1.0f / s;
#pragma unroll
                for (int n = 0; n < 4; ++n) {
                    int col = bn + wc * 64 + n * 16 + l15;
                    R[(size_t)(grow + j) * N + col] = f2bf(e[n] * inv * vsv[n]);
                }
            }
        }
    }
}

// ---------- host launch ----------
extern "C" void kernel_launch(void* const* d_in, const int* in_sizes, int n_in,
                              void* d_out, int out_size, void* d_ws, size_t ws_size,
                              hipStream_t stream) {
    const float* target = (const float*)d_in[0];
    const float* source = (const float*)d_in[1];
    const float* value  = (const float*)d_in[2];
    const float* Wq = (const float*)d_in[3];
    const float* bq = (const float*)d_in[4];
    const float* Wk = (const float*)d_in[5];
    const float* bk = (const float*)d_in[6];
    const float* Wv = (const float*)d_in[7];
    const float* bv = (const float*)d_in[8];
    const float* Wo = (const float*)d_in[9];
    const float* bo = (const float*)d_in[10];
    float* out = (float*)d_out;

    char* ws = (char*)d_ws;
    float*          part1  = (float*)(ws);                    // 2*8*4096*4   = 256KB
    float*          sums   = (float*)(ws + 262144);           // 2*4096*4     = 32KB
    float*          part2  = (float*)(ws + 294912);           // 2*32*1024*4  = 256KB
    float*          kvsum  = (float*)(ws + 557056);           // 2*1024*4     = 8KB
    unsigned short* tgt_bf = (unsigned short*)(ws + 1048576);  // 4096*1024*2 = 8MB
    unsigned short* wq_t   = (unsigned short*)(ws + 9437184);  // 1024*1024*2 = 2MB
    unsigned short* wo_t   = (unsigned short*)(ws + 11534336); // 4096*1024*2 = 8MB
    unsigned short* Rb     = (unsigned short*)(ws + 19922944); // 4096*1024*2 = 8MB

    // 1) column sums over V
    colsum_partial<<<dim3(16, 8, 2), 256, 0, stream>>>(source, value, part1);
    colsum_reduce<<<32, 256, 0, stream>>>(part1, sums);

    // 2) Ksum/Vsum GEMVs
    gemv_partial<<<dim3(4, 32, 2), 256, 0, stream>>>(Wk, Wv, sums, part2);
    gemv_reduce<<<8, 256, 0, stream>>>(part2, bk, bv, kvsum);

    // 3) casts / transposes to bf16
    cast_bf16<<<4096, 256, 0, stream>>>(target, tgt_bf, BP * DMODEL / 4);
    transpose_cast<<<dim3(HDK / 32, DMODEL / 32), dim3(32, 8), 0, stream>>>(Wq, wq_t, DMODEL, HDK);
    transpose_cast<<<dim3(DLLM / 32, HDK / 32), dim3(32, 8), 0, stream>>>(Wo, wo_t, HDK, DLLM);

    // 4) fused: S = target @ Wq; R = softmax_head(0.125*(S+bq)*Ksum) * Vsum (bf16)
    gemm_k<1><<<dim3(HDK / BN, BP / BM), 256, 0, stream>>>(
        tgt_bf, wq_t, nullptr, bq, kvsum, Rb, BP, HDK, DMODEL);

    // 5) out = R @ Wo + bo
    gemm_k<0><<<dim3(DLLM / BN, BP / BM), 256, 0, stream>>>(
        Rb, wo_t, out, bo, kvsum, nullptr, BP, DLLM, HDK);
}

// Round 3
// 118.276 us; speedup vs baseline: 1.0389x; 1.0141x over previous
//
#include <hip/hip_runtime.h>

// ---------- constants (problem is fixed-shape) ----------
#define BB   16
#define PP   256
#define BP   4096        // B*P
#define DMODEL 1024
#define VV   1000
#define DLLM 4096
#define HH   16
#define DK   64
#define HDK  1024        // H*DK

using f32x4 = __attribute__((ext_vector_type(4))) float;
using s16x8 = __attribute__((ext_vector_type(8))) short;

__device__ __forceinline__ unsigned short f2bf(float f) {
    unsigned int u = __builtin_bit_cast(unsigned int, f);
    u = (u + 0x7FFFu + ((u >> 16) & 1u)) >> 16;   // RNE
    return (unsigned short)u;
}

// ---------- K1a: partial column sums of source/value (V x 4096 f32) ----------
__global__ void colsum_partial(const float* __restrict__ src0,
                               const float* __restrict__ src1,
                               float* __restrict__ part) {
    int col   = blockIdx.x * 256 + threadIdx.x;   // 0..4095
    int chunk = blockIdx.y;                        // 0..39 (25 rows each)
    int z     = blockIdx.z;                        // 0=source 1=value
    const float* src = z ? src1 : src0;
    int r0 = chunk * 25;
    float acc = 0.f;
    for (int r = 0; r < 25; ++r)
        acc += src[(size_t)(r0 + r) * DLLM + col];
    part[((z * 40 + chunk) * DLLM) + col] = acc;
}

// ---------- K1b: reduce partials -> sums[2][4096] ----------
__global__ void colsum_reduce(const float* __restrict__ part, float* __restrict__ sums) {
    int idx = blockIdx.x * 256 + threadIdx.x;      // 0..8191
    int z = idx >> 12, col = idx & 4095;
    float acc = 0.f;
    for (int c = 0; c < 40; ++c) acc += part[(size_t)(z * 40 + c) * DLLM + col];
    sums[idx] = acc;
}

// ---------- K2a: partial GEMV  part[z][chunk][c] = sum_r sums[z][r]*W[r][c] ----------
__global__ void gemv_partial(const float* __restrict__ Wk, const float* __restrict__ Wv,
                             const float* __restrict__ sums, float* __restrict__ part) {
    __shared__ float vec[64];
    int c     = blockIdx.x * 256 + threadIdx.x;    // 0..1023
    int chunk = blockIdx.y;                         // 0..63 (64 rows each)
    int z     = blockIdx.z;                         // 0=K 1=V
    const float* W = z ? Wv : Wk;
    const float* v = sums + z * DLLM;
    if (threadIdx.x < 64) vec[threadIdx.x] = v[chunk * 64 + threadIdx.x];
    __syncthreads();
    float acc = 0.f;
    int r0 = chunk * 64;
    for (int r = 0; r < 64; ++r)
        acc += vec[r] * W[(size_t)(r0 + r) * HDK + c];
    part[((z * 64 + chunk) * HDK) + c] = acc;
}

// ---------- K2b: reduce -> kvsum[0..1023]=Ksum, [1024..2047]=Vsum ----------
__global__ void gemv_reduce(const float* __restrict__ part,
                            const float* __restrict__ bk, const float* __restrict__ bv,
                            float* __restrict__ kvsum) {
    int idx = blockIdx.x * 256 + threadIdx.x;       // 0..2047
    int z = idx >> 10, c = idx & 1023;
    float acc = 0.f;
    for (int ch = 0; ch < 64; ++ch) acc += part[(size_t)(z * 64 + ch) * HDK + c];
    acc += (float)VV * (z ? bv[c] : bk[c]);
    kvsum[idx] = acc;
}

// ---------- K3a: cast f32 -> bf16 (vectorized, n4 = n/4) ----------
__global__ void cast_bf16(const float* __restrict__ src, unsigned short* __restrict__ dst, int n4) {
    int idx = blockIdx.x * 256 + threadIdx.x;
    if (idx >= n4) return;
    float4 v = reinterpret_cast<const float4*>(src)[idx];
    ushort4 o = make_ushort4(f2bf(v.x), f2bf(v.y), f2bf(v.z), f2bf(v.w));
    reinterpret_cast<ushort4*>(dst)[idx] = o;
}

// ---------- K3b: transpose + cast: src (R x C f32) -> dst (C x R bf16) ----------
__global__ void transpose_cast(const float* __restrict__ src, unsigned short* __restrict__ dst,
                               int R, int C) {
    __shared__ float tile[32][33];
    int tx = threadIdx.x, ty = threadIdx.y;         // 32 x 8
    int c0 = blockIdx.x * 32, r0 = blockIdx.y * 32;
#pragma unroll
    for (int j = 0; j < 4; ++j)
        tile[ty + j * 8][tx] = src[(size_t)(r0 + ty + j * 8) * C + c0 + tx];
    __syncthreads();
#pragma unroll
    for (int j = 0; j < 4; ++j)
        dst[(size_t)(c0 + ty + j * 8) * R + r0 + tx] = f2bf(tile[tx][ty + j * 8]);
}

// ---------- GEMM (reg-staged, dbuf LDS, 1 barrier/K-step): C = A(MxK) * Bt(NxK)^T ----------
// EPI=0: C(f32) = A*B^T + bias
// EPI=1: per-(row,head) softmax over the wave's 64-col head group, times Vsum,
//        write bf16 R. bias param = bq; kvsum[0:1024]=Ksum, [1024:2048]=Vsum.
#define BM 128
#define BN 128
#define BK2 32
#define LSTR 40   // 32 + 8 bf16 pad: 80B rows -> ds_read_b128 ~2-way (free)

template<int EPI>
__global__ __launch_bounds__(256, 4)
void gemm_k(const unsigned short* __restrict__ A, const unsigned short* __restrict__ Bt,
            float* __restrict__ C, const float* __restrict__ bias,
            const float* __restrict__ kvsum, unsigned short* __restrict__ R,
            int M, int N, int K) {
    __shared__ unsigned short Asm[2][BM * LSTR];   // 2 x 10 KB
    __shared__ unsigned short Bsm[2][BN * LSTR];   // 2 x 10 KB  (40 KB total)
    const int t = threadIdx.x;
    const int wave = t >> 6, lane = t & 63;
    const int wr = wave >> 1, wc = wave & 1;        // 2x2 waves, 64x64 out each
    const int bm = blockIdx.y * BM;
    const int bn = blockIdx.x * BN;
    const int l15 = lane & 15;
    const int kgrp = lane >> 4;                     // 0..3

    // staging: chunk cid in [0,1024): row=cid>>2 (of 128), 16B at col (cid&3)*8.
    // thread t covers cid=t (rows 0..63) and cid=t+256 (rows 64..127): fully
    // coalesced 16B/lane per issue.
    const int srow = t >> 2, sc = (t & 3) * 8;
    const unsigned short* Ag0 = A + (size_t)(bm + srow) * K + sc;
    const unsigned short* Bg0 = Bt + (size_t)(bn + srow) * K + sc;
    const size_t rstep = (size_t)64 * K;
    const int off0 = srow * LSTR + sc, off1 = off0 + 64 * LSTR;

    f32x4 acc[4][4] = {};
    float4 ra0, ra1, rb0, rb1;

    // prologue: stage tile 0 into buf 0
    ra0 = *reinterpret_cast<const float4*>(Ag0);
    ra1 = *reinterpret_cast<const float4*>(Ag0 + rstep);
    rb0 = *reinterpret_cast<const float4*>(Bg0);
    rb1 = *reinterpret_cast<const float4*>(Bg0 + rstep);
    *reinterpret_cast<float4*>(&Asm[0][off0]) = ra0;
    *reinterpret_cast<float4*>(&Asm[0][off1]) = ra1;
    *reinterpret_cast<float4*>(&Bsm[0][off0]) = rb0;
    *reinterpret_cast<float4*>(&Bsm[0][off1]) = rb1;

    const int nK = K / BK2;
    int cur = 0;
    for (int ks = 0; ks < nK; ++ks) {
        __syncthreads();   // buf[cur] writes visible; prefetch regs consumed before this
        if (ks + 1 < nK) { // issue next-tile loads; land under MFMA, consumed at ds_write
            const unsigned short* Ap = Ag0 + (size_t)(ks + 1) * BK2;
            const unsigned short* Bp = Bg0 + (size_t)(ks + 1) * BK2;
            ra0 = *reinterpret_cast<const float4*>(Ap);
            ra1 = *reinterpret_cast<const float4*>(Ap + rstep);
            rb0 = *reinterpret_cast<const float4*>(Bp);
            rb1 = *reinterpret_cast<const float4*>(Bp + rstep);
        }
        s16x8 af[4], bfr[4];
#pragma unroll
        for (int m = 0; m < 4; ++m)
            af[m] = *reinterpret_cast<const s16x8*>(
                &Asm[cur][(wr * 64 + m * 16 + l15) * LSTR + kgrp * 8]);
#pragma unroll
        for (int n = 0; n < 4; ++n)
            bfr[n] = *reinterpret_cast<const s16x8*>(
                &Bsm[cur][(wc * 64 + n * 16 + l15) * LSTR + kgrp * 8]);
#pragma unroll
        for (int m = 0; m < 4; ++m)
#pragma unroll
            for (int n = 0; n < 4; ++n)
                acc[m][n] = __builtin_amdgcn_mfma_f32_16x16x32_bf16(af[m], bfr[n], acc[m][n], 0, 0, 0);
        if (ks + 1 < nK) {
            *reinterpret_cast<float4*>(&Asm[cur ^ 1][off0]) = ra0;
            *reinterpret_cast<float4*>(&Asm[cur ^ 1][off1]) = ra1;
            *reinterpret_cast<float4*>(&Bsm[cur ^ 1][off0]) = rb0;
            *reinterpret_cast<float4*>(&Bsm[cur ^ 1][off1]) = rb1;
        }
        cur ^= 1;
    }

    // C/D layout: col = lane&15, row = (lane>>4)*4 + reg j  (guide §3, m89/m91)
    if (EPI == 0) {
#pragma unroll
        for (int m = 0; m < 4; ++m) {
            int grow = bm + wr * 64 + m * 16 + kgrp * 4;
#pragma unroll
            for (int n = 0; n < 4; ++n) {
                int gcol = bn + wc * 64 + n * 16 + l15;
                float bb = bias[gcol];
#pragma unroll
                for (int j = 0; j < 4; ++j)
                    C[(size_t)(grow + j) * N + gcol] = acc[m][n][j] + bb;
            }
        }
    } else {
        // wave's 64-col span = exactly one head. softmax over head dim =
        // reduce over n regs + 16-lane-group shfl (offsets 8,4,2,1 within l15 group... 
        // lanes with same kgrp differ only in l15; reduce across l15 via xor 1..8).
        float bqv[4], ksv[4], vsv[4];
#pragma unroll
        for (int n = 0; n < 4; ++n) {
            int col = bn + wc * 64 + n * 16 + l15;
            bqv[n] = bias[col];
            ksv[n] = kvsum[col];
            vsv[n] = kvsum[HDK + col];
        }
#pragma unroll
        for (int m = 0; m < 4; ++m) {
            int grow = bm + wr * 64 + m * 16 + kgrp * 4;
#pragma unroll
            for (int j = 0; j < 4; ++j) {
                float x[4];
#pragma unroll
                for (int n = 0; n < 4; ++n)
                    x[n] = 0.125f * (acc[m][n][j] + bqv[n]) * ksv[n];
                float mx = fmaxf(fmaxf(x[0], x[1]), fmaxf(x[2], x[3]));
#pragma unroll
                for (int off = 8; off; off >>= 1) mx = fmaxf(mx, __shfl_xor(mx, off));
                float e[4], s = 0.f;
#pragma unroll
                for (int n = 0; n < 4; ++n) { e[n] = __expf(x[n] - mx); s += e[n]; }
#pragma unroll
                for (int off = 8; off; off >>= 1) s += __shfl_xor(s, off);
                float inv = 1.0f / s;
#pragma unroll
                for (int n = 0; n < 4; ++n) {
                    int col = bn + wc * 64 + n * 16 + l15;
                    R[(size_t)(grow + j) * N + col] = f2bf(e[n] * inv * vsv[n]);
                }
            }
        }
    }
}

// ---------- host launch ----------
extern "C" void kernel_launch(void* const* d_in, const int* in_sizes, int n_in,
                              void* d_out, int out_size, void* d_ws, size_t ws_size,
                              hipStream_t stream) {
    const float* target = (const float*)d_in[0];
    const float* source = (const float*)d_in[1];
    const float* value  = (const float*)d_in[2];
    const float* Wq = (const float*)d_in[3];
    const float* bq = (const float*)d_in[4];
    const float* Wk = (const float*)d_in[5];
    const float* bk = (const float*)d_in[6];
    const float* Wv = (const float*)d_in[7];
    const float* bv = (const float*)d_in[8];
    const float* Wo = (const float*)d_in[9];
    const float* bo = (const float*)d_in[10];
    float* out = (float*)d_out;

    char* ws = (char*)d_ws;
    float*          part1  = (float*)(ws);                     // 2*40*4096*4 = 1.25MB
    float*          sums   = (float*)(ws + 0x180000);          // 32KB
    float*          part2  = (float*)(ws + 0x190000);          // 2*64*1024*4 = 512KB
    float*          kvsum  = (float*)(ws + 0x210000);          // 8KB
    unsigned short* tgt_bf = (unsigned short*)(ws + 0x400000);  // 8MB
    unsigned short* wq_t   = (unsigned short*)(ws + 0xC00000);  // 2MB
    unsigned short* wo_t   = (unsigned short*)(ws + 0xE00000);  // 8MB
    unsigned short* Rb     = (unsigned short*)(ws + 0x1600000); // 8MB

    // 1) column sums over V
    colsum_partial<<<dim3(16, 40, 2), 256, 0, stream>>>(source, value, part1);
    colsum_reduce<<<32, 256, 0, stream>>>(part1, sums);

    // 2) Ksum/Vsum GEMVs
    gemv_partial<<<dim3(4, 64, 2), 256, 0, stream>>>(Wk, Wv, sums, part2);
    gemv_reduce<<<8, 256, 0, stream>>>(part2, bk, bv, kvsum);

    // 3) casts / transposes to bf16
    cast_bf16<<<4096, 256, 0, stream>>>(target, tgt_bf, BP * DMODEL / 4);
    transpose_cast<<<dim3(HDK / 32, DMODEL / 32), dim3(32, 8), 0, stream>>>(Wq, wq_t, DMODEL, HDK);
    transpose_cast<<<dim3(DLLM / 32, HDK / 32), dim3(32, 8), 0, stream>>>(Wo, wo_t, HDK, DLLM);

    // 4) fused: S = target @ Wq; R = softmax_head(0.125*(S+bq)*Ksum) * Vsum (bf16)
    gemm_k<1><<<dim3(HDK / BN, BP / BM), 256, 0, stream>>>(
        tgt_bf, wq_t, nullptr, bq, kvsum, Rb, BP, HDK, DMODEL);

    // 5) out = R @ Wo + bo
    gemm_k<0><<<dim3(DLLM / BN, BP / BM), 256, 0, stream>>>(
        Rb, wo_t, out, bo, kvsum, nullptr, BP, DLLM, HDK);
}

// Round 4
// 97.828 us; speedup vs baseline: 1.2561x; 1.2090x over previous
//
#include <hip/hip_runtime.h>

// ---------- constants (problem is fixed-shape) ----------
#define BB   16
#define PP   256
#define BP   4096        // B*P
#define DMODEL 1024
#define VV   1000
#define DLLM 4096
#define HH   16
#define DK   64
#define HDK  1024        // H*DK

using f32x4 = __attribute__((ext_vector_type(4))) float;
using s16x8 = __attribute__((ext_vector_type(8))) short;

__device__ __forceinline__ unsigned short f2bf(float f) {
    unsigned int u = __builtin_bit_cast(unsigned int, f);
    u = (u + 0x7FFFu + ((u >> 16) & 1u)) >> 16;   // RNE
    return (unsigned short)u;
}

__device__ __forceinline__ void gload_lds16(const unsigned short* g, unsigned short* lds) {
    __builtin_amdgcn_global_load_lds(
        (const __attribute__((address_space(1))) void*)g,
        (__attribute__((address_space(3))) void*)lds,
        16, 0, 0);
}

// ---------- MEGA1: colsum_partial ∪ cast_bf16 ∪ transpose(Wq) ∪ transpose(Wo) ----------
__device__ __forceinline__ void transpose_body(const float* __restrict__ src,
                                               unsigned short* __restrict__ dst,
                                               int R, int C, int bx, int by, int t,
                                               float (*tile)[33]) {
    int tx = t & 31, ty = t >> 5;                   // 32 x 8
    int c0 = bx * 32, r0 = by * 32;
#pragma unroll
    for (int j = 0; j < 4; ++j)
        tile[ty + j * 8][tx] = src[(size_t)(r0 + ty + j * 8) * C + c0 + tx];
    __syncthreads();
#pragma unroll
    for (int j = 0; j < 4; ++j)
        dst[(size_t)(c0 + ty + j * 8) * R + r0 + tx] = f2bf(tile[tx][ty + j * 8]);
}

__global__ void mega1(const float* __restrict__ src0, const float* __restrict__ src1,
                      float* __restrict__ part1,
                      const float* __restrict__ target, unsigned short* __restrict__ tgt_bf,
                      const float* __restrict__ Wq, unsigned short* __restrict__ wq_t,
                      const float* __restrict__ Wo, unsigned short* __restrict__ wo_t) {
    __shared__ float tile[32][33];
    int b = blockIdx.x, t = threadIdx.x;
    if (b < 1280) {
        // colsum_partial: 16 x 40 x 2
        int x = b & 15, y = (b >> 4) % 40, z = b / 640;
        int col = x * 256 + t;
        const float* src = z ? src1 : src0;
        int r0 = y * 25;
        float acc = 0.f;
        for (int r = 0; r < 25; ++r)
            acc += src[(size_t)(r0 + r) * DLLM + col];
        part1[((z * 40 + y) * DLLM) + col] = acc;
    } else if (b < 1280 + 4096) {
        int idx = (b - 1280) * 256 + t;             // < 1048576 = BP*DMODEL/4
        float4 v = reinterpret_cast<const float4*>(target)[idx];
        ushort4 o = make_ushort4(f2bf(v.x), f2bf(v.y), f2bf(v.z), f2bf(v.w));
        reinterpret_cast<ushort4*>(tgt_bf)[idx] = o;
    } else if (b < 1280 + 4096 + 1024) {
        int b2 = b - 5376;
        transpose_body(Wq, wq_t, DMODEL, HDK, b2 & 31, b2 >> 5, t, tile);
    } else {
        int b2 = b - 6400;
        transpose_body(Wo, wo_t, HDK, DLLM, b2 & 127, b2 >> 7, t, tile);
    }
}

// ---------- gemv_partial2 (inlines colsum_reduce) ----------
__global__ void gemv_partial2(const float* __restrict__ Wk, const float* __restrict__ Wv,
                              const float* __restrict__ part1, float* __restrict__ part2) {
    __shared__ float vec[64];
    int c     = blockIdx.x * 256 + threadIdx.x;    // 0..1023
    int chunk = blockIdx.y;                         // 0..63 (64 rows each)
    int z     = blockIdx.z;                         // 0=K 1=V
    const float* W = z ? Wv : Wk;
    if (threadIdx.x < 64) {
        int r = chunk * 64 + threadIdx.x;
        float a = 0.f;
        for (int p = 0; p < 40; ++p)
            a += part1[(size_t)(z * 40 + p) * DLLM + r];
        vec[threadIdx.x] = a;
    }
    __syncthreads();
    float acc = 0.f;
    int r0 = chunk * 64;
    for (int r = 0; r < 64; ++r)
        acc += vec[r] * W[(size_t)(r0 + r) * HDK + c];
    part2[((z * 64 + chunk) * HDK) + c] = acc;
}

__global__ void gemv_reduce(const float* __restrict__ part,
                            const float* __restrict__ bk, const float* __restrict__ bv,
                            float* __restrict__ kvsum) {
    int idx = blockIdx.x * 256 + threadIdx.x;       // 0..2047
    int z = idx >> 10, c = idx & 1023;
    float acc = 0.f;
    for (int ch = 0; ch < 64; ++ch) acc += part[(size_t)(z * 64 + ch) * HDK + c];
    acc += (float)VV * (z ? bv[c] : bk[c]);
    kvsum[idx] = acc;
}

// ---------- GEMM1 (128², reg-staged dbuf) with fused softmax epilogue ----------
#define BM 128
#define BN 128
#define BK2 32
#define LSTR 40

__global__ __launch_bounds__(256, 4)
void gemm_k(const unsigned short* __restrict__ A, const unsigned short* __restrict__ Bt,
            const float* __restrict__ bias,
            const float* __restrict__ kvsum, unsigned short* __restrict__ R,
            int M, int N, int K) {
    __shared__ unsigned short Asm[2][BM * LSTR];
    __shared__ unsigned short Bsm[2][BN * LSTR];
    const int t = threadIdx.x;
    const int wave = t >> 6, lane = t & 63;
    const int wr = wave >> 1, wc = wave & 1;
    const int bm = blockIdx.y * BM;
    const int bn = blockIdx.x * BN;
    const int l15 = lane & 15;
    const int kgrp = lane >> 4;

    const int srow = t >> 2, sc = (t & 3) * 8;
    const unsigned short* Ag0 = A + (size_t)(bm + srow) * K + sc;
    const unsigned short* Bg0 = Bt + (size_t)(bn + srow) * K + sc;
    const size_t rstep = (size_t)64 * K;
    const int off0 = srow * LSTR + sc, off1 = off0 + 64 * LSTR;

    f32x4 acc[4][4] = {};
    float4 ra0, ra1, rb0, rb1;

    ra0 = *reinterpret_cast<const float4*>(Ag0);
    ra1 = *reinterpret_cast<const float4*>(Ag0 + rstep);
    rb0 = *reinterpret_cast<const float4*>(Bg0);
    rb1 = *reinterpret_cast<const float4*>(Bg0 + rstep);
    *reinterpret_cast<float4*>(&Asm[0][off0]) = ra0;
    *reinterpret_cast<float4*>(&Asm[0][off1]) = ra1;
    *reinterpret_cast<float4*>(&Bsm[0][off0]) = rb0;
    *reinterpret_cast<float4*>(&Bsm[0][off1]) = rb1;

    const int nK = K / BK2;
    int cur = 0;
    for (int ks = 0; ks < nK; ++ks) {
        __syncthreads();
        if (ks + 1 < nK) {
            const unsigned short* Ap = Ag0 + (size_t)(ks + 1) * BK2;
            const unsigned short* Bp = Bg0 + (size_t)(ks + 1) * BK2;
            ra0 = *reinterpret_cast<const float4*>(Ap);
            ra1 = *reinterpret_cast<const float4*>(Ap + rstep);
            rb0 = *reinterpret_cast<const float4*>(Bp);
            rb1 = *reinterpret_cast<const float4*>(Bp + rstep);
        }
        s16x8 af[4], bfr[4];
#pragma unroll
        for (int m = 0; m < 4; ++m)
            af[m] = *reinterpret_cast<const s16x8*>(
                &Asm[cur][(wr * 64 + m * 16 + l15) * LSTR + kgrp * 8]);
#pragma unroll
        for (int n = 0; n < 4; ++n)
            bfr[n] = *reinterpret_cast<const s16x8*>(
                &Bsm[cur][(wc * 64 + n * 16 + l15) * LSTR + kgrp * 8]);
#pragma unroll
        for (int m = 0; m < 4; ++m)
#pragma unroll
            for (int n = 0; n < 4; ++n)
                acc[m][n] = __builtin_amdgcn_mfma_f32_16x16x32_bf16(af[m], bfr[n], acc[m][n], 0, 0, 0);
        if (ks + 1 < nK) {
            *reinterpret_cast<float4*>(&Asm[cur ^ 1][off0]) = ra0;
            *reinterpret_cast<float4*>(&Asm[cur ^ 1][off1]) = ra1;
            *reinterpret_cast<float4*>(&Bsm[cur ^ 1][off0]) = rb0;
            *reinterpret_cast<float4*>(&Bsm[cur ^ 1][off1]) = rb1;
        }
        cur ^= 1;
    }

    // fused softmax epilogue (wave's 64 cols = one head)
    float bqv[4], ksv[4], vsv[4];
#pragma unroll
    for (int n = 0; n < 4; ++n) {
        int col = bn + wc * 64 + n * 16 + l15;
        bqv[n] = bias[col];
        ksv[n] = kvsum[col];
        vsv[n] = kvsum[HDK + col];
    }
#pragma unroll
    for (int m = 0; m < 4; ++m) {
        int grow = bm + wr * 64 + m * 16 + kgrp * 4;
#pragma unroll
        for (int j = 0; j < 4; ++j) {
            float x[4];
#pragma unroll
            for (int n = 0; n < 4; ++n)
                x[n] = 0.125f * (acc[m][n][j] + bqv[n]) * ksv[n];
            float mx = fmaxf(fmaxf(x[0], x[1]), fmaxf(x[2], x[3]));
#pragma unroll
            for (int off = 8; off; off >>= 1) mx = fmaxf(mx, __shfl_xor(mx, off));
            float e[4], s = 0.f;
#pragma unroll
            for (int n = 0; n < 4; ++n) { e[n] = __expf(x[n] - mx); s += e[n]; }
#pragma unroll
            for (int off = 8; off; off >>= 1) s += __shfl_xor(s, off);
            float inv = 1.0f / s;
#pragma unroll
            for (int n = 0; n < 4; ++n) {
                int col = bn + wc * 64 + n * 16 + l15;
                R[(size_t)(grow + j) * N + col] = f2bf(e[n] * inv * vsv[n]);
            }
        }
    }
}

// ---------- GEMM2: 256x256 tile, 8 waves, 4-buffer BK=32, counted vmcnt, T2 swizzle ----------
// LDS involution (rule #21): logical (row, 16B-slot c in 0..3) <-> physical
// super-row sr=row>>1, slot8 = (c + 4*(row&1)) ^ (sr&7). Applied to the GLOBAL
// source address at staging (LDS dest stays linear for global_load_lds) and to
// the ds_read address. 16-lane column reads hit all 8 slots 2x -> conflict-free.
#define G2_NT 32   // K/32 = 1024/32

__global__ __launch_bounds__(512, 2)
void gemm256(const unsigned short* __restrict__ A, const unsigned short* __restrict__ Bt,
             float* __restrict__ C, const float* __restrict__ bias, int N, int K) {
    __shared__ unsigned short Asm[4][8192];   // 4 x 16KB
    __shared__ unsigned short Bsm[4][8192];   // 4 x 16KB  -> 128KB total
    const int t = threadIdx.x;
    const int w = t >> 6, lane = t & 63;
    const int wr = w >> 2, wc = w & 3;        // 2M x 4N waves; per-wave out 128x64
    const int l15 = lane & 15, kgrp = lane >> 4;
    const int bm = blockIdx.y * 256, bn = blockIdx.x * 256;

    // staging: issue i covers physical super-rows i*64 + w*8 + (lane>>3), slot lane&7
    size_t goffA[2], goffB[2];
    int ldsoff[2];
    {
        int s8 = lane & 7, jj = lane >> 3;
#pragma unroll
        for (int i = 0; i < 2; ++i) {
            int sr = i * 64 + w * 8 + jj;
            int x = s8 ^ (sr & 7);            // = c + 4b (inverse swizzle)
            int row = sr * 2 + (x >> 2);
            int col = (x & 3) * 8;
            goffA[i] = (size_t)(bm + row) * K + col;
            goffB[i] = (size_t)(bn + row) * K + col;
            ldsoff[i] = i * 4096 + w * 512;   // ushort units; HW adds lane*16B
        }
    }
    // swizzled ds_read addresses (ushort units), loop-invariant
    int ra[8], rb[4];
#pragma unroll
    for (int m = 0; m < 8; ++m) {
        int r = wr * 128 + m * 16 + l15;
        int s8 = (kgrp + 4 * (r & 1)) ^ ((r >> 1) & 7);
        ra[m] = (r >> 1) * 64 + s8 * 8;
    }
#pragma unroll
    for (int n = 0; n < 4; ++n) {
        int r = wc * 64 + n * 16 + l15;
        int s8 = (kgrp + 4 * (r & 1)) ^ ((r >> 1) & 7);
        rb[n] = (r >> 1) * 64 + s8 * 8;
    }

    f32x4 acc[8][4] = {};

#define STAGE_A(tile_, buf_) do { size_t k0_ = (size_t)(tile_) * 32; \
    gload_lds16(A + goffA[0] + k0_, &Asm[buf_][ldsoff[0]]); \
    gload_lds16(A + goffA[1] + k0_, &Asm[buf_][ldsoff[1]]); } while (0)
#define STAGE_B(tile_, buf_) do { size_t k0_ = (size_t)(tile_) * 32; \
    gload_lds16(Bt + goffB[0] + k0_, &Bsm[buf_][ldsoff[0]]); \
    gload_lds16(Bt + goffB[1] + k0_, &Bsm[buf_][ldsoff[1]]); } while (0)

    // prologue: tiles 0,1 staged; wait until tile 0 (4 oldest) landed
    STAGE_A(0, 0); STAGE_B(0, 0);
    STAGE_A(1, 1); STAGE_B(1, 1);
    asm volatile("s_waitcnt vmcnt(4)" ::: "memory");
    __builtin_amdgcn_s_barrier();

    for (int tk = 0; tk < G2_NT; ++tk) {
        const int buf = tk & 3;
        const unsigned short* As = Asm[buf];
        const unsigned short* Bs = Bsm[buf];
        // ---- phase A: quad m0..3, all n; prefetch A of tile tk+2 ----
        s16x8 af[4], bfr[4];
#pragma unroll
        for (int m = 0; m < 4; ++m)
            af[m] = *reinterpret_cast<const s16x8*>(&As[ra[m]]);
#pragma unroll
        for (int n = 0; n < 4; ++n)
            bfr[n] = *reinterpret_cast<const s16x8*>(&Bs[rb[n]]);
        if (tk < G2_NT - 2) STAGE_A(tk + 2, (tk + 2) & 3);
        __builtin_amdgcn_s_barrier();
        __builtin_amdgcn_s_setprio(1);
#pragma unroll
        for (int m = 0; m < 4; ++m)
#pragma unroll
            for (int n = 0; n < 4; ++n)
                acc[m][n] = __builtin_amdgcn_mfma_f32_16x16x32_bf16(af[m], bfr[n], acc[m][n], 0, 0, 0);
        __builtin_amdgcn_s_setprio(0);
        __builtin_amdgcn_s_barrier();
        // ---- phase B: quad m4..7 (reuse bfr); prefetch B of tile tk+2 ----
        s16x8 af2[4];
#pragma unroll
        for (int m = 0; m < 4; ++m)
            af2[m] = *reinterpret_cast<const s16x8*>(&As[ra[m + 4]]);
        if (tk < G2_NT - 2) STAGE_B(tk + 2, (tk + 2) & 3);
        if (tk < G2_NT - 2)
            asm volatile("s_waitcnt vmcnt(4)" ::: "memory");   // tile tk+1 fully landed
        else if (tk == G2_NT - 2)
            asm volatile("s_waitcnt vmcnt(0)" ::: "memory");   // drain for last tile
        __builtin_amdgcn_s_barrier();
        __builtin_amdgcn_s_setprio(1);
#pragma unroll
        for (int m = 0; m < 4; ++m)
#pragma unroll
            for (int n = 0; n < 4; ++n)
                acc[m + 4][n] = __builtin_amdgcn_mfma_f32_16x16x32_bf16(af2[m], bfr[n], acc[m + 4][n], 0, 0, 0);
        __builtin_amdgcn_s_setprio(0);
        __builtin_amdgcn_s_barrier();
    }
#undef STAGE_A
#undef STAGE_B

    // epilogue: C/D layout col = lane&15, row = (lane>>4)*4 + j
#pragma unroll
    for (int m = 0; m < 8; ++m) {
        int grow = bm + wr * 128 + m * 16 + kgrp * 4;
#pragma unroll
        for (int n = 0; n < 4; ++n) {
            int gcol = bn + wc * 64 + n * 16 + l15;
            float bb = bias[gcol];
#pragma unroll
            for (int j = 0; j < 4; ++j)
                C[(size_t)(grow + j) * N + gcol] = acc[m][n][j] + bb;
        }
    }
}

// ---------- host launch ----------
extern "C" void kernel_launch(void* const* d_in, const int* in_sizes, int n_in,
                              void* d_out, int out_size, void* d_ws, size_t ws_size,
                              hipStream_t stream) {
    const float* target = (const float*)d_in[0];
    const float* source = (const float*)d_in[1];
    const float* value  = (const float*)d_in[2];
    const float* Wq = (const float*)d_in[3];
    const float* bq = (const float*)d_in[4];
    const float* Wk = (const float*)d_in[5];
    const float* bk = (const float*)d_in[6];
    const float* Wv = (const float*)d_in[7];
    const float* bv = (const float*)d_in[8];
    const float* Wo = (const float*)d_in[9];
    const float* bo = (const float*)d_in[10];
    float* out = (float*)d_out;

    char* ws = (char*)d_ws;
    float*          part1  = (float*)(ws);                      // 2*40*4096*4 = 1.25MB
    float*          part2  = (float*)(ws + 0x180000);           // 512KB
    float*          kvsum  = (float*)(ws + 0x210000);           // 8KB
    unsigned short* tgt_bf = (unsigned short*)(ws + 0x400000);  // 8MB
    unsigned short* wq_t   = (unsigned short*)(ws + 0xC00000);  // 2MB
    unsigned short* wo_t   = (unsigned short*)(ws + 0xE00000);  // 8MB
    unsigned short* Rb     = (unsigned short*)(ws + 0x1600000); // 8MB

    // 1) fused prep: colsum partials + cast(target) + transpose(Wq) + transpose(Wo)
    mega1<<<10496, 256, 0, stream>>>(source, value, part1, target, tgt_bf, Wq, wq_t, Wo, wo_t);

    // 2) Ksum/Vsum GEMV (inlines colsum reduce) + bias fold
    gemv_partial2<<<dim3(4, 64, 2), 256, 0, stream>>>(Wk, Wv, part1, part2);
    gemv_reduce<<<8, 256, 0, stream>>>(part2, bk, bv, kvsum);

    // 3) fused: S = target @ Wq; R = softmax_head(0.125*(S+bq)*Ksum) * Vsum (bf16)
    gemm_k<<<dim3(HDK / BN, BP / BM), 256, 0, stream>>>(
        tgt_bf, wq_t, bq, kvsum, Rb, BP, HDK, DMODEL);

    // 4) out = R @ Wo + bo  (256² 8-phase-style schedule)
    gemm256<<<dim3(DLLM / 256, BP / 256), 512, 0, stream>>>(
        Rb, wo_t, out, bo, DLLM, HDK);
}

// Round 5
// 95.271 us; speedup vs baseline: 1.2898x; 1.0268x over previous
//
#include <hip/hip_runtime.h>

// ---------- constants (problem is fixed-shape) ----------
#define BB   16
#define PP   256
#define BP   4096        // B*P
#define DMODEL 1024
#define VV   1000
#define DLLM 4096
#define HH   16
#define DK   64
#define HDK  1024        // H*DK

using f32x4 = __attribute__((ext_vector_type(4))) float;
using s16x8 = __attribute__((ext_vector_type(8))) short;

__device__ __forceinline__ unsigned short f2bf(float f) {
    unsigned int u = __builtin_bit_cast(unsigned int, f);
    u = (u + 0x7FFFu + ((u >> 16) & 1u)) >> 16;   // RNE
    return (unsigned short)u;
}

__device__ __forceinline__ void gload_lds16(const unsigned short* g, unsigned short* lds) {
    __builtin_amdgcn_global_load_lds(
        (const __attribute__((address_space(1))) void*)g,
        (__attribute__((address_space(3))) void*)lds,
        16, 0, 0);
}

// ---------- MEGA1: colsum_partial ∪ cast_bf16 ∪ transpose(Wq) ∪ transpose(Wo) ----------
__device__ __forceinline__ void transpose_body(const float* __restrict__ src,
                                               unsigned short* __restrict__ dst,
                                               int R, int C, int bx, int by, int t,
                                               float (*tile)[33]) {
    int tx = t & 31, ty = t >> 5;                   // 32 x 8
    int c0 = bx * 32, r0 = by * 32;
#pragma unroll
    for (int j = 0; j < 4; ++j)
        tile[ty + j * 8][tx] = src[(size_t)(r0 + ty + j * 8) * C + c0 + tx];
    __syncthreads();
#pragma unroll
    for (int j = 0; j < 4; ++j)
        dst[(size_t)(c0 + ty + j * 8) * R + r0 + tx] = f2bf(tile[tx][ty + j * 8]);
}

__global__ void mega1(const float* __restrict__ src0, const float* __restrict__ src1,
                      float* __restrict__ part1,
                      const float* __restrict__ target, unsigned short* __restrict__ tgt_bf,
                      const float* __restrict__ Wq, unsigned short* __restrict__ wq_t,
                      const float* __restrict__ Wo, unsigned short* __restrict__ wo_t) {
    __shared__ float tile[32][33];
    int b = blockIdx.x, t = threadIdx.x;
    if (b < 1280) {
        int x = b & 15, y = (b >> 4) % 40, z = b / 640;
        int col = x * 256 + t;
        const float* src = z ? src1 : src0;
        int r0 = y * 25;
        float acc = 0.f;
        for (int r = 0; r < 25; ++r)
            acc += src[(size_t)(r0 + r) * DLLM + col];
        part1[((z * 40 + y) * DLLM) + col] = acc;
    } else if (b < 1280 + 4096) {
        int idx = (b - 1280) * 256 + t;
        float4 v = reinterpret_cast<const float4*>(target)[idx];
        ushort4 o = make_ushort4(f2bf(v.x), f2bf(v.y), f2bf(v.z), f2bf(v.w));
        reinterpret_cast<ushort4*>(tgt_bf)[idx] = o;
    } else if (b < 1280 + 4096 + 1024) {
        int b2 = b - 5376;
        transpose_body(Wq, wq_t, DMODEL, HDK, b2 & 31, b2 >> 5, t, tile);
    } else {
        int b2 = b - 6400;
        transpose_body(Wo, wo_t, HDK, DLLM, b2 & 127, b2 >> 7, t, tile);
    }
}

// ---------- gemv_partial2 (inlines colsum_reduce) ----------
__global__ void gemv_partial2(const float* __restrict__ Wk, const float* __restrict__ Wv,
                              const float* __restrict__ part1, float* __restrict__ part2) {
    __shared__ float vec[64];
    int c     = blockIdx.x * 256 + threadIdx.x;
    int chunk = blockIdx.y;
    int z     = blockIdx.z;
    const float* W = z ? Wv : Wk;
    if (threadIdx.x < 64) {
        int r = chunk * 64 + threadIdx.x;
        float a = 0.f;
        for (int p = 0; p < 40; ++p)
            a += part1[(size_t)(z * 40 + p) * DLLM + r];
        vec[threadIdx.x] = a;
    }
    __syncthreads();
    float acc = 0.f;
    int r0 = chunk * 64;
    for (int r = 0; r < 64; ++r)
        acc += vec[r] * W[(size_t)(r0 + r) * HDK + c];
    part2[((z * 64 + chunk) * HDK) + c] = acc;
}

__global__ void gemv_reduce(const float* __restrict__ part,
                            const float* __restrict__ bk, const float* __restrict__ bv,
                            float* __restrict__ kvsum) {
    int idx = blockIdx.x * 256 + threadIdx.x;
    int z = idx >> 10, c = idx & 1023;
    float acc = 0.f;
    for (int ch = 0; ch < 64; ++ch) acc += part[(size_t)(z * 64 + ch) * HDK + c];
    acc += (float)VV * (z ? bv[c] : bk[c]);
    kvsum[idx] = acc;
}

// ---------- unified counted-vmcnt GEMM: C = A(MxK bf16) * Bt(NxK bf16)^T ----------
// BK=32, 4 LDS buffers, distance-3 prefetch via global_load_lds, ONE barrier
// per K-tile, swizzled LDS (r4's involution, measured 0 conflicts).
// EPI=0: C(f32) += bias.  EPI=1: fused per-head softmax -> bf16 R.
// Requires: K % 32 == 0, K/32 >= 4; BMt/(16*WM*WN)==2 staging instrs/wave.
template<int EPI, int BMt, int BNt, int WM, int WN>
__global__ __launch_bounds__(WM * WN * 64, 2)
void gemm_ctd(const unsigned short* __restrict__ A, const unsigned short* __restrict__ Bt,
              float* __restrict__ C, const float* __restrict__ bias,
              const float* __restrict__ kvsum, unsigned short* __restrict__ R,
              int N, int K, int gx) {
    constexpr int WAVES = WM * WN;
    constexpr int M_REP = BMt / WM / 16;   // 16x16 frags per wave along M
    __shared__ unsigned short Asm[4][BMt * 32];
    __shared__ unsigned short Bsm[4][BNt * 32];

    // bijective XCD swizzle (grid % 8 == 0)
    const int nwg = gridDim.x, q = nwg >> 3;
    const int nb = (blockIdx.x & 7) * q + (blockIdx.x >> 3);
    const int bm = (nb / gx) * BMt;
    const int bn = (nb % gx) * BNt;

    const int t = threadIdx.x;
    const int w = t >> 6, lane = t & 63;
    const int wr = w / WN, wc = w % WN;
    const int l15 = lane & 15, kgrp = lane >> 4;

    // staging map (r4 involution): physical super-row sr (128B = 8 x 16B slots),
    // slot s8; logical slot = s8 ^ (sr&7); row = sr*2 + (log>>2), col16 = log&3.
    size_t goffA[2], goffB[2];
    int ldso[2];
    {
        int s8 = lane & 7, jj = lane >> 3;
#pragma unroll
        for (int i = 0; i < 2; ++i) {
            int sr = (i * WAVES + w) * 8 + jj;
            int x = s8 ^ (sr & 7);
            int row = sr * 2 + (x >> 2);
            int col = (x & 3) * 8;
            goffA[i] = (size_t)(bm + row) * K + col;
            goffB[i] = (size_t)(bn + row) * K + col;
            ldso[i] = (i * WAVES + w) * 512;   // ushort units; HW adds lane*16B
        }
    }
    // swizzled ds_read addresses (ushort units)
    int ra[M_REP], rb[4];
#pragma unroll
    for (int m = 0; m < M_REP; ++m) {
        int r = wr * (M_REP * 16) + m * 16 + l15;
        int s8 = (kgrp + 4 * (r & 1)) ^ ((r >> 1) & 7);
        ra[m] = (r >> 1) * 64 + s8 * 8;
    }
#pragma unroll
    for (int n = 0; n < 4; ++n) {
        int r = wc * 64 + n * 16 + l15;
        int s8 = (kgrp + 4 * (r & 1)) ^ ((r >> 1) & 7);
        rb[n] = (r >> 1) * 64 + s8 * 8;
    }

    f32x4 acc[M_REP][4] = {};

#define STAGE(t_, b_) do { size_t k0_ = (size_t)(t_) * 32;            \
    gload_lds16(A + goffA[0] + k0_, &Asm[b_][ldso[0]]);               \
    gload_lds16(A + goffA[1] + k0_, &Asm[b_][ldso[1]]);               \
    gload_lds16(Bt + goffB[0] + k0_, &Bsm[b_][ldso[0]]);              \
    gload_lds16(Bt + goffB[1] + k0_, &Bsm[b_][ldso[1]]); } while (0)

    const int nT = K >> 5;
    // prologue: stage tiles 0..2 (distance 3)
    STAGE(0, 0); STAGE(1, 1); STAGE(2, 2);
    asm volatile("s_waitcnt vmcnt(8)" ::: "memory");   // tile 0 landed
    __builtin_amdgcn_s_barrier();

    for (int tk = 0; tk < nT; ++tk) {
        const int b = tk & 3;
        s16x8 af[M_REP], bfr[4];
#pragma unroll
        for (int m = 0; m < M_REP; ++m)
            af[m] = *reinterpret_cast<const s16x8*>(&Asm[b][ra[m]]);
#pragma unroll
        for (int n = 0; n < 4; ++n)
            bfr[n] = *reinterpret_cast<const s16x8*>(&Bsm[b][rb[n]]);
        if (tk < nT - 3) STAGE(tk + 3, (tk + 3) & 3);
        __builtin_amdgcn_s_setprio(1);
#pragma unroll
        for (int m = 0; m < M_REP; ++m)
#pragma unroll
            for (int n = 0; n < 4; ++n)
                acc[m][n] = __builtin_amdgcn_mfma_f32_16x16x32_bf16(af[m], bfr[n], acc[m][n], 0, 0, 0);
        __builtin_amdgcn_s_setprio(0);
        // counted waits: ensure tile tk+1 fully landed before next tile's reads
        if (tk < nT - 3)       asm volatile("s_waitcnt vmcnt(8)" ::: "memory");
        else if (tk == nT - 3) asm volatile("s_waitcnt vmcnt(4)" ::: "memory");
        else if (tk == nT - 2) asm volatile("s_waitcnt vmcnt(0)" ::: "memory");
        if (tk + 1 < nT) __builtin_amdgcn_s_barrier();
    }
#undef STAGE

    // epilogue: C/D layout col = lane&15, row = (lane>>4)*4 + j
    if (EPI == 0) {
#pragma unroll
        for (int m = 0; m < M_REP; ++m) {
            int grow = bm + wr * (M_REP * 16) + m * 16 + kgrp * 4;
#pragma unroll
            for (int n = 0; n < 4; ++n) {
                int gcol = bn + wc * 64 + n * 16 + l15;
                float bb = bias[gcol];
#pragma unroll
                for (int j = 0; j < 4; ++j)
                    C[(size_t)(grow + j) * N + gcol] = acc[m][n][j] + bb;
            }
        }
    } else {
        // wave's 64-col span = one head: softmax over head dim, scale by Vsum
        float bqv[4], ksv[4], vsv[4];
#pragma unroll
        for (int n = 0; n < 4; ++n) {
            int col = bn + wc * 64 + n * 16 + l15;
            bqv[n] = bias[col];
            ksv[n] = kvsum[col];
            vsv[n] = kvsum[HDK + col];
        }
#pragma unroll
        for (int m = 0; m < M_REP; ++m) {
            int grow = bm + wr * (M_REP * 16) + m * 16 + kgrp * 4;
#pragma unroll
            for (int j = 0; j < 4; ++j) {
                float x[4];
#pragma unroll
                for (int n = 0; n < 4; ++n)
                    x[n] = 0.125f * (acc[m][n][j] + bqv[n]) * ksv[n];
                float mx = fmaxf(fmaxf(x[0], x[1]), fmaxf(x[2], x[3]));
#pragma unroll
                for (int off = 8; off; off >>= 1) mx = fmaxf(mx, __shfl_xor(mx, off));
                float e[4], s = 0.f;
#pragma unroll
                for (int n = 0; n < 4; ++n) { e[n] = __expf(x[n] - mx); s += e[n]; }
#pragma unroll
                for (int off = 8; off; off >>= 1) s += __shfl_xor(s, off);
                float inv = 1.0f / s;
#pragma unroll
                for (int n = 0; n < 4; ++n) {
                    int col = bn + wc * 64 + n * 16 + l15;
                    R[(size_t)(grow + j) * N + col] = f2bf(e[n] * inv * vsv[n]);
                }
            }
        }
    }
}

// ---------- host launch ----------
extern "C" void kernel_launch(void* const* d_in, const int* in_sizes, int n_in,
                              void* d_out, int out_size, void* d_ws, size_t ws_size,
                              hipStream_t stream) {
    const float* target = (const float*)d_in[0];
    const float* source = (const float*)d_in[1];
    const float* value  = (const float*)d_in[2];
    const float* Wq = (const float*)d_in[3];
    const float* bq = (const float*)d_in[4];
    const float* Wk = (const float*)d_in[5];
    const float* bk = (const float*)d_in[6];
    const float* Wv = (const float*)d_in[7];
    const float* bv = (const float*)d_in[8];
    const float* Wo = (const float*)d_in[9];
    const float* bo = (const float*)d_in[10];
    float* out = (float*)d_out;

    char* ws = (char*)d_ws;
    float*          part1  = (float*)(ws);                      // 1.25MB
    float*          part2  = (float*)(ws + 0x180000);           // 512KB
    float*          kvsum  = (float*)(ws + 0x210000);           // 8KB
    unsigned short* tgt_bf = (unsigned short*)(ws + 0x400000);  // 8MB
    unsigned short* wq_t   = (unsigned short*)(ws + 0xC00000);  // 2MB
    unsigned short* wo_t   = (unsigned short*)(ws + 0xE00000);  // 8MB
    unsigned short* Rb     = (unsigned short*)(ws + 0x1600000); // 8MB

    // 1) fused prep: colsum partials + cast(target) + transpose(Wq) + transpose(Wo)
    mega1<<<10496, 256, 0, stream>>>(source, value, part1, target, tgt_bf, Wq, wq_t, Wo, wo_t);

    // 2) Ksum/Vsum GEMV + bias fold
    gemv_partial2<<<dim3(4, 64, 2), 256, 0, stream>>>(Wk, Wv, part1, part2);
    gemv_reduce<<<8, 256, 0, stream>>>(part2, bk, bv, kvsum);

    // 3) fused: S = target @ Wq; R = softmax_head(0.125*(S+bq)*Ksum) * Vsum (bf16)
    gemm_ctd<1, 128, 128, 2, 2><<<256, 256, 0, stream>>>(
        tgt_bf, wq_t, nullptr, bq, kvsum, Rb, HDK, DMODEL, HDK / 128);

    // 4) out = R @ Wo + bo  (256² single-barrier counted-vmcnt schedule)
    gemm_ctd<0, 256, 256, 2, 4><<<256, 512, 0, stream>>>(
        Rb, wo_t, out, bo, nullptr, nullptr, DLLM, HDK, DLLM / 256);
}